// Round 4
// baseline (419.614 us; speedup 1.0000x reference)
//
#include <hip/hip_runtime.h>

#define B_  4
#define N_  2048
#define H_  16
#define HD_ 1024

typedef short  bf16x8 __attribute__((ext_vector_type(8)));
typedef short  bf16x4 __attribute__((ext_vector_type(4)));
typedef float  f32x4  __attribute__((ext_vector_type(4)));

// round-half-up bf16: max error 0.5 ulp (same bound as RNE; only ties differ)
static __device__ __forceinline__ unsigned short f2bf(float f) {
    unsigned int u = __builtin_bit_cast(unsigned int, f);
    return (unsigned short)((u + 0x8000u) >> 16);
}
// pack two floats -> (bf16(hi)<<16)|bf16(lo), 3 VALU ops (RHU rounding)
static __device__ __forceinline__ unsigned f2bf2pack(float lo, float hi) {
    unsigned a = __builtin_bit_cast(unsigned, lo) + 0x8000u;
    unsigned b = __builtin_bit_cast(unsigned, hi) + 0x8000u;
    return __builtin_amdgcn_perm(b, a, 0x07060302u);
}

// ---------------- projection: 256 tokens/block, register-resident W ----------------
// grid (N/256, H, B*3); z = b*3 + p
// q,k out: [b,h,n,64] bf16 (q pre-scaled by 0.125*log2e); v out transposed [b,h,64,n]
// W fragments live in VGPRs (no LDS, no staging barrier); x A-fragments load
// directly from global; only the output transpose goes through LDS (9.2 KB).
__global__ __launch_bounds__(256, 4) void proj_kernel(
    const float* __restrict__ Qv, const float* __restrict__ Kv,
    const float* __restrict__ Vv, const float* __restrict__ WQ,
    const float* __restrict__ WK, const float* __restrict__ WV,
    unsigned short* __restrict__ qs, unsigned short* __restrict__ ks,
    unsigned short* __restrict__ vt)
{
    __shared__ __align__(16) unsigned short sb[64][72];

    const int tid  = threadIdx.x;
    const int wq   = tid >> 6;
    const int lane = tid & 63;
    const int l15  = lane & 15;
    const int quad = lane >> 4;

    const int i0 = blockIdx.x * 256;
    const int h  = blockIdx.y;
    const int bz = blockIdx.z;
    const int b  = bz / 3;
    const int p  = bz - b * 3;

    const size_t bh = (size_t)b * H_ + h;
    const float* W   = (p == 0) ? WQ : (p == 1) ? WK : WV;
    const float* inp = ((p == 0) ? Qv : (p == 1) ? Kv : Vv)
                       + ((size_t)b * N_ + i0) * HD_ + h * 64;

    // W B-fragments, straight from global (L2-resident): row t*16+l15, cols kh*32+quad*8
    bf16x8 bw[4][2];
    #pragma unroll
    for (int t = 0; t < 4; ++t)
        #pragma unroll
        for (int kh = 0; kh < 2; ++kh) {
            const float* wp = W + (size_t)(t * 16 + l15) * 64 + kh * 32 + quad * 8;
            float4 f0 = *reinterpret_cast<const float4*>(wp);
            float4 f1 = *reinterpret_cast<const float4*>(wp + 4);
            uint4 u = uint4{f2bf2pack(f0.x, f0.y), f2bf2pack(f0.z, f0.w),
                            f2bf2pack(f1.x, f1.y), f2bf2pack(f1.z, f1.w)};
            bw[t][kh] = __builtin_bit_cast(bf16x8, u);
        }

    const float scl = (p == 0) ? 0.180336880f : 1.f;  // 0.125 * log2(e)
    unsigned short* dst  = ((p == 0) ? qs : ks) + ((size_t)bh * N_ + i0) * 64;
    unsigned short* vdst = vt + (size_t)bh * 64 * N_ + i0;

    // x A-fragment raw loads for sub-tile st into a named float4[4] (static idx only)
#define LOAD_X(st, XR) {                                                          \
        const float* xp = inp + (size_t)((st) * 64 + wq * 16 + l15) * HD_;        \
        XR[0] = *reinterpret_cast<const float4*>(xp + quad * 8);                  \
        XR[1] = *reinterpret_cast<const float4*>(xp + quad * 8 + 4);              \
        XR[2] = *reinterpret_cast<const float4*>(xp + 32 + quad * 8);             \
        XR[3] = *reinterpret_cast<const float4*>(xp + 32 + quad * 8 + 4);         \
    }

#define DO_TILE(st, XR, FIRST) {                                                  \
        bf16x8 ax0, ax1;                                                          \
        { uint4 u = uint4{f2bf2pack(XR[0].x, XR[0].y), f2bf2pack(XR[0].z, XR[0].w),\
                          f2bf2pack(XR[1].x, XR[1].y), f2bf2pack(XR[1].z, XR[1].w)};\
          ax0 = __builtin_bit_cast(bf16x8, u); }                                  \
        { uint4 u = uint4{f2bf2pack(XR[2].x, XR[2].y), f2bf2pack(XR[2].z, XR[2].w),\
                          f2bf2pack(XR[3].x, XR[3].y), f2bf2pack(XR[3].z, XR[3].w)};\
          ax1 = __builtin_bit_cast(bf16x8, u); }                                  \
        f32x4 C[4];                                                               \
        _Pragma("unroll")                                                         \
        for (int t = 0; t < 4; ++t) {                                             \
            C[t] = f32x4{0.f, 0.f, 0.f, 0.f};                                     \
            C[t] = __builtin_amdgcn_mfma_f32_16x16x32_bf16(ax0, bw[t][0], C[t], 0, 0, 0); \
            C[t] = __builtin_amdgcn_mfma_f32_16x16x32_bf16(ax1, bw[t][1], C[t], 0, 0, 0); \
        }                                                                         \
        if (!(FIRST)) __syncthreads();  /* prior store-reads done before sb reuse */ \
        if (p < 2) {                                                              \
            _Pragma("unroll")                                                     \
            for (int t = 0; t < 4; ++t)                                           \
                _Pragma("unroll")                                                 \
                for (int r = 0; r < 4; ++r)                                       \
                    sb[wq * 16 + quad * 4 + r][t * 16 + l15] = f2bf(C[t][r] * scl); \
            __syncthreads();                                                      \
            _Pragma("unroll")                                                     \
            for (int v = 0; v < 2; ++v) {                                         \
                int idx = tid + v * 256;                                          \
                int row = idx >> 3, c0 = (idx & 7) * 8;                           \
                *reinterpret_cast<uint4*>(dst + (size_t)((st) * 64 + row) * 64 + c0) = \
                    *reinterpret_cast<const uint4*>(&sb[row][c0]);                \
            }                                                                     \
        } else {                                                                  \
            _Pragma("unroll")                                                     \
            for (int t = 0; t < 4; ++t) {                                         \
                uint2 u;                                                          \
                u.x = f2bf2pack(C[t][0], C[t][1]);                                \
                u.y = f2bf2pack(C[t][2], C[t][3]);                                \
                *reinterpret_cast<uint2*>(&sb[t * 16 + l15][wq * 16 + quad * 4]) = u; \
            }                                                                     \
            __syncthreads();                                                      \
            _Pragma("unroll")                                                     \
            for (int v = 0; v < 2; ++v) {                                         \
                int idx = tid + v * 256;                                          \
                int d = idx >> 3, c0 = (idx & 7) * 8;                             \
                *reinterpret_cast<uint4*>(vdst + (size_t)d * N_ + (st) * 64 + c0) = \
                    *reinterpret_cast<const uint4*>(&sb[d][c0]);                  \
            }                                                                     \
        }                                                                         \
    }

    float4 x0[4], x1[4];
    LOAD_X(0, x0);
    LOAD_X(1, x1);
    DO_TILE(0, x0, true);
    LOAD_X(2, x0);                 // in flight across tile-1 compute+stores
    DO_TILE(1, x1, false);
    LOAD_X(3, x1);                 // in flight across tile-2 compute+stores
    DO_TILE(2, x0, false);
    DO_TILE(3, x1, false);
#undef LOAD_X
#undef DO_TILE
}

// ---------------- transposed flash attention, 8 waves ----------------
// S^T = K Q^T, O^T = V^T P^T. P never touches LDS: the S^T C-layout registers
// ARE the P B-fragment under the k-permutation sigma(k). S acc initialized with
// the k-mask bias (kb depends only on column j = C-layout index of S^T).
// 512 threads = 8 waves x 32 q-rows: 4 waves/SIMD at 2 blocks/CU -> the block's
// own waves overlap VALU (exp2/pack) with MFMA on the same SIMD.
// grid: (N/256, B*H).
__global__ __launch_bounds__(512, 4) void attn_kernel(
    const unsigned short* __restrict__ qs, const unsigned short* __restrict__ ks,
    const unsigned short* __restrict__ vt, const int* __restrict__ maskp,
    float* __restrict__ out)
{
    __shared__ __align__(16) unsigned short Ks[64][72];   // stride 36 dw: b128 reads 2-way (free)
    __shared__ __align__(16) unsigned short Vt[64][68];   // stride 34 dw: b64 reads conflict-free
    __shared__ float kb[64];

    const int tid  = threadIdx.x;
    const int w    = tid >> 6;          // 0..7
    const int lane = tid & 63;
    const int l15  = lane & 15;
    const int quad = lane >> 4;

    const int i0 = blockIdx.x * 256;
    const int bh = blockIdx.y;
    const int b  = bh >> 4;
    const int h  = bh & 15;
    const int qrow0 = i0 + w * 32;      // 32 rows per wave

    // Q fragments (B-operand) for 2 row-tiles, straight from global
    bf16x8 aq[2][2];
    float  qm[2];
    #pragma unroll
    for (int rt = 0; rt < 2; ++rt) {
        const unsigned short* qrow = qs + ((size_t)bh * N_ + qrow0 + rt * 16 + l15) * 64;
        aq[rt][0] = *reinterpret_cast<const bf16x8*>(qrow + quad * 8);
        aq[rt][1] = *reinterpret_cast<const bf16x8*>(qrow + 32 + quad * 8);
        qm[rt] = maskp[b * N_ + qrow0 + rt * 16 + l15] ? 1.f : 0.f;
    }

    bf16x8 aones;
    #pragma unroll
    for (int j = 0; j < 8; ++j) aones[j] = (short)0x3F80;

    f32x4 O[2][4];     // [rt][ct2] : O^T[d-block ct2][qrow-block rt]
    f32x4 L[2];
    #pragma unroll
    for (int rt = 0; rt < 2; ++rt) {
        L[rt] = f32x4{0.f, 0.f, 0.f, 0.f};
        #pragma unroll
        for (int c = 0; c < 4; ++c) O[rt][c] = f32x4{0.f, 0.f, 0.f, 0.f};
    }

    const unsigned short* kbase = ks + (size_t)bh * N_ * 64;
    const unsigned short* vbase = vt + (size_t)bh * 64 * N_;

    for (int kv0 = 0; kv0 < N_; kv0 += 64) {
        __syncthreads();
        // stage K rows [64][64] (512 uint4) and V^T rows (1024 uint2)
        {
            int r = tid >> 3, g = tid & 7;
            *reinterpret_cast<uint4*>(&Ks[r][g * 8]) =
                *reinterpret_cast<const uint4*>(kbase + (size_t)(kv0 + r) * 64 + g * 8);
        }
        #pragma unroll
        for (int it = 0; it < 2; ++it) {
            int idx = tid + it * 512;
            int r = idx >> 4, g2 = idx & 15;
            *reinterpret_cast<uint2*>(&Vt[r][g2 * 4]) =
                *reinterpret_cast<const uint2*>(vbase + (size_t)r * N_ + kv0 + g2 * 4);
        }
        if (tid < 64) kb[tid] = maskp[b * N_ + kv0 + tid] ? 0.f : -1e30f;
        __syncthreads();

        // K A-fragments (shared across both rt) and V A-fragments
        bf16x8 ak[4][2];
        #pragma unroll
        for (int ct = 0; ct < 4; ++ct)
            #pragma unroll
            for (int kh = 0; kh < 2; ++kh)
                ak[ct][kh] = *reinterpret_cast<const bf16x8*>(&Ks[ct * 16 + l15][kh * 32 + quad * 8]);

        bf16x8 av[4][2];
        #pragma unroll
        for (int ct = 0; ct < 4; ++ct)
            #pragma unroll
            for (int kh = 0; kh < 2; ++kh) {
                bf16x4 lo = *reinterpret_cast<const bf16x4*>(&Vt[ct * 16 + l15][kh * 32 + quad * 4]);
                bf16x4 hi = *reinterpret_cast<const bf16x4*>(&Vt[ct * 16 + l15][kh * 32 + 16 + quad * 4]);
                av[ct][kh] = bf16x8{lo[0], lo[1], lo[2], lo[3], hi[0], hi[1], hi[2], hi[3]};
            }

        f32x4 kbv[4];
        #pragma unroll
        for (int ct = 0; ct < 4; ++ct)
            kbv[ct] = *reinterpret_cast<const f32x4*>(&kb[ct * 16 + quad * 4]);

        #pragma unroll
        for (int rt = 0; rt < 2; ++rt) {
            // S^T: lane holds S[qrow=rt*16+l15][j=16ct+4q+r]; acc starts at kb[j]
            f32x4 S[4];
            #pragma unroll
            for (int ct = 0; ct < 4; ++ct) {
                S[ct] = kbv[ct];
                #pragma unroll
                for (int kh = 0; kh < 2; ++kh)
                    S[ct] = __builtin_amdgcn_mfma_f32_16x16x32_bf16(ak[ct][kh], aq[rt][kh], S[ct], 0, 0, 0);
            }
            // masked exp2 (q pre-scaled by log2e); pack directly into P B-fragments
            unsigned pk[4][2];
            #pragma unroll
            for (int ct = 0; ct < 4; ++ct) {
                float e0 = __builtin_amdgcn_exp2f(S[ct][0] * qm[rt]);
                float e1 = __builtin_amdgcn_exp2f(S[ct][1] * qm[rt]);
                float e2 = __builtin_amdgcn_exp2f(S[ct][2] * qm[rt]);
                float e3 = __builtin_amdgcn_exp2f(S[ct][3] * qm[rt]);
                pk[ct][0] = f2bf2pack(e0, e1);
                pk[ct][1] = f2bf2pack(e2, e3);
            }
            bf16x8 ap[2];
            #pragma unroll
            for (int kh = 0; kh < 2; ++kh) {
                uint4 u = uint4{pk[2 * kh][0], pk[2 * kh][1], pk[2 * kh + 1][0], pk[2 * kh + 1][1]};
                ap[kh] = __builtin_bit_cast(bf16x8, u);
            }
            // row-sums: D[m][n=qrow] = sum_k P — every lane gets its own qrow's L
            #pragma unroll
            for (int kh = 0; kh < 2; ++kh)
                L[rt] = __builtin_amdgcn_mfma_f32_16x16x32_bf16(aones, ap[kh], L[rt], 0, 0, 0);
            // O^T += V^T P^T
            #pragma unroll
            for (int ct = 0; ct < 4; ++ct)
                #pragma unroll
                for (int kh = 0; kh < 2; ++kh)
                    O[rt][ct] = __builtin_amdgcn_mfma_f32_16x16x32_bf16(av[ct][kh], ap[kh], O[rt][ct], 0, 0, 0);
        }
    }

    // epilogue: lane (q,l15) holds O^T[d=16ct+4q+r][qrow=rt*16+l15]; L[rt] components all equal
    #pragma unroll
    for (int rt = 0; rt < 2; ++rt) {
        float inv = 1.f / L[rt][0];
        float* orow = out + ((size_t)b * N_ + qrow0 + rt * 16 + l15) * HD_ + h * 64 + quad * 4;
        #pragma unroll
        for (int ct = 0; ct < 4; ++ct)
            #pragma unroll
            for (int r = 0; r < 4; ++r)
                orow[ct * 16 + r] = O[rt][ct][r] * inv;
    }
}

extern "C" void kernel_launch(void* const* d_in, const int* in_sizes, int n_in,
                              void* d_out, int out_size, void* d_ws, size_t ws_size,
                              hipStream_t stream)
{
    const float* Qv  = (const float*)d_in[0];
    const float* Kv  = (const float*)d_in[1];
    const float* Vv  = (const float*)d_in[2];
    const float* WQ  = (const float*)d_in[3];
    const float* WK  = (const float*)d_in[4];
    const float* WV  = (const float*)d_in[5];
    const int*   msk = (const int*)d_in[6];
    float* out = (float*)d_out;

    const size_t per = (size_t)B_ * H_ * N_ * 64;   // 8.4M elems, bf16
    unsigned short* qsb = (unsigned short*)d_ws;
    unsigned short* ksb = qsb + per;
    unsigned short* vtb = ksb + per;

    proj_kernel<<<dim3(N_ / 256, H_, B_ * 3), 256, 0, stream>>>(Qv, Kv, Vv, WQ, WK, WV, qsb, ksb, vtb);
    attn_kernel<<<dim3(N_ / 256, B_ * H_), 512, 0, stream>>>(qsb, ksb, vtb, msk, out);
}